// Round 1
// baseline (2661.262 us; speedup 1.0000x reference)
//
#include <hip/hip_runtime.h>
#include <hip/hip_bf16.h>

// Problem constants (fixed by the reference)
#define NN 50000
#define FIN 128
#define NH 2
#define C1 64
#define C2 32
#define NE 800000
#define NEDGE (NE + NN)   // edges + self loops
#define NEG 0.2f

// ---------------- utilities ----------------
__device__ __forceinline__ void atomicMaxF(float* addr, float val) {
    // classic float atomic-max: int-max for >=0, uint-min for <0
    if (val >= 0.0f) atomicMax((int*)addr, __float_as_int(val));
    else             atomicMin((unsigned int*)addr, __float_as_uint(val));
}

// ---------------- init ----------------
__global__ void init_layer1(float* __restrict__ m, float* __restrict__ s,
                            float* __restrict__ out1) {
    const int total = NN * FIN;
    for (int i = blockIdx.x * blockDim.x + threadIdx.x; i < total;
         i += gridDim.x * blockDim.x) {
        out1[i] = 0.0f;
        if (i < NN * NH) { m[i] = -INFINITY; s[i] = 0.0f; }
    }
}

__global__ void init_layer2(float* __restrict__ m, float* __restrict__ s,
                            float* __restrict__ out, const float* __restrict__ bias) {
    const int total = NN * C2;
    for (int i = blockIdx.x * blockDim.x + threadIdx.x; i < total;
         i += gridDim.x * blockDim.x) {
        out[i] = bias[i & (C2 - 1)];
        if (i < NN * NH) { m[i] = -INFINITY; s[i] = 0.0f; }
    }
}

// ---------------- GEMM (K=128 fixed), optional fused relu(x+bias) on load ----
template<int BN, bool RELU_BIAS>
__global__ __launch_bounds__(256) void gemm_k128(const float* __restrict__ X,
                                                 const float* __restrict__ Wm,
                                                 const float* __restrict__ bias,
                                                 float* __restrict__ Y, int M) {
    constexpr int GROUPS = BN / 16;      // 8 (BN=128) or 4 (BN=64)
    constexpr int BM = 256 / GROUPS;     // 32 or 64
    __shared__ __align__(16) float Xs[BM][33];   // +1 pad: kills 8-way bank conflict on Xs[r][k]
    __shared__ __align__(16) float Ws[32][BN];

    const int tid = threadIdx.x;
    const int r  = tid / GROUPS;
    const int c0 = (tid % GROUPS) * 16;
    const int rowBase = blockIdx.x * BM;

    float4 acc0 = {0,0,0,0}, acc1 = {0,0,0,0}, acc2 = {0,0,0,0}, acc3 = {0,0,0,0};

    for (int kk = 0; kk < 4; ++kk) {
        // stage X chunk [BM][32]
        constexpr int XV = BM * 8;   // float4 count
        #pragma unroll
        for (int i = tid; i < XV; i += 256) {
            const int xr = i >> 3, xc = (i & 7) * 4;
            const int grow = rowBase + xr;
            float4 v = {0,0,0,0};
            if (grow < M) {
                v = *reinterpret_cast<const float4*>(&X[grow * FIN + kk * 32 + xc]);
                if (RELU_BIAS) {
                    const float4 b = *reinterpret_cast<const float4*>(&bias[kk * 32 + xc]);
                    v.x = fmaxf(v.x + b.x, 0.0f);
                    v.y = fmaxf(v.y + b.y, 0.0f);
                    v.z = fmaxf(v.z + b.z, 0.0f);
                    v.w = fmaxf(v.w + b.w, 0.0f);
                }
            }
            Xs[xr][xc] = v.x; Xs[xr][xc+1] = v.y; Xs[xr][xc+2] = v.z; Xs[xr][xc+3] = v.w;
        }
        // stage W chunk [32][BN]
        constexpr int WV = 32 * BN / 4;
        #pragma unroll
        for (int i = tid; i < WV; i += 256) {
            const int wr = i / (BN / 4), wc = (i % (BN / 4)) * 4;
            *reinterpret_cast<float4*>(&Ws[wr][wc]) =
                *reinterpret_cast<const float4*>(&Wm[(kk * 32 + wr) * BN + wc]);
        }
        __syncthreads();
        #pragma unroll
        for (int k = 0; k < 32; ++k) {
            const float xv = Xs[r][k];
            const float4* wrow = reinterpret_cast<const float4*>(&Ws[k][c0]);
            const float4 w0 = wrow[0], w1 = wrow[1], w2 = wrow[2], w3 = wrow[3];
            acc0.x += xv * w0.x; acc0.y += xv * w0.y; acc0.z += xv * w0.z; acc0.w += xv * w0.w;
            acc1.x += xv * w1.x; acc1.y += xv * w1.y; acc1.z += xv * w1.z; acc1.w += xv * w1.w;
            acc2.x += xv * w2.x; acc2.y += xv * w2.y; acc2.z += xv * w2.z; acc2.w += xv * w2.w;
            acc3.x += xv * w3.x; acc3.y += xv * w3.y; acc3.z += xv * w3.z; acc3.w += xv * w3.w;
        }
        __syncthreads();
    }
    const int grow = rowBase + r;
    if (grow < M) {
        float4* yp = reinterpret_cast<float4*>(&Y[grow * BN + c0]);
        yp[0] = acc0; yp[1] = acc1; yp[2] = acc2; yp[3] = acc3;
    }
}

// ---------------- attention dot products: a_src/a_dst [N,H] ----------------
template<int C>
__global__ void attdot(const float* __restrict__ Hm,
                       const float* __restrict__ att_src,
                       const float* __restrict__ att_dst,
                       float* __restrict__ asrc, float* __restrict__ adst) {
    const int i = blockIdx.x * blockDim.x + threadIdx.x;   // over N*H
    if (i >= NN * NH) return;
    const int n = i / NH, h = i % NH;
    const float* hp = Hm + (n * NH + h) * C;
    const float* as = att_src + h * C;
    const float* ad = att_dst + h * C;
    float s1 = 0.0f, s2 = 0.0f;
    #pragma unroll
    for (int c = 0; c < C; c += 4) {
        const float4 hv = *reinterpret_cast<const float4*>(hp + c);
        const float4 a1 = *reinterpret_cast<const float4*>(as + c);
        const float4 a2 = *reinterpret_cast<const float4*>(ad + c);
        s1 += hv.x * a1.x + hv.y * a1.y + hv.z * a1.z + hv.w * a1.w;
        s2 += hv.x * a2.x + hv.y * a2.y + hv.z * a2.z + hv.w * a2.w;
    }
    asrc[i] = s1; adst[i] = s2;
}

// ---------------- edge pass A: leaky-relu scores + segment max ----------------
__global__ void edge_max(const int* __restrict__ ei,
                         const float* __restrict__ asrc, const float* __restrict__ adst,
                         float* __restrict__ ebuf, float* __restrict__ m) {
    const int i = blockIdx.x * blockDim.x + threadIdx.x;
    if (i >= NEDGE) return;
    int src, dst;
    if (i < NE) { src = ei[i]; dst = ei[NE + i]; } else { src = dst = i - NE; }
    #pragma unroll
    for (int h = 0; h < NH; ++h) {
        float v = asrc[src * NH + h] + adst[dst * NH + h];
        v = v > 0.0f ? v : NEG * v;
        ebuf[i * NH + h] = v;
        atomicMaxF(&m[dst * NH + h], v);
    }
}

// ---------------- edge pass B: exp + segment sum ----------------
__global__ void edge_exp(const int* __restrict__ ei,
                         float* __restrict__ ebuf,
                         const float* __restrict__ m, float* __restrict__ s) {
    const int i = blockIdx.x * blockDim.x + threadIdx.x;
    if (i >= NEDGE) return;
    const int dst = (i < NE) ? ei[NE + i] : i - NE;
    #pragma unroll
    for (int h = 0; h < NH; ++h) {
        const float p = __expf(ebuf[i * NH + h] - m[dst * NH + h]);
        ebuf[i * NH + h] = p;
        atomicAdd(&s[dst * NH + h], p);
    }
}

// ---------------- edge pass C: weighted aggregation ----------------
// C = per-head channels. MEAN=true: layer2, out[dst*C + c] += 0.5*alpha*h  (head mean)
template<int C, bool MEAN>
__global__ void edge_aggr(const int* __restrict__ ei,
                          const float* __restrict__ ebuf, const float* __restrict__ s,
                          const float* __restrict__ Hm, float* __restrict__ out) {
    constexpr int TPE = NH * C / 4;   // threads per edge (32 or 16)
    const int t = blockIdx.x * blockDim.x + threadIdx.x;
    const int i = t / TPE;
    if (i >= NEDGE) return;
    const int lane = t % TPE;
    const int h  = lane / (C / 4);
    const int cq = (lane % (C / 4)) * 4;
    int src, dst;
    if (i < NE) { src = ei[i]; dst = ei[NE + i]; } else { src = dst = i - NE; }
    float alpha = ebuf[i * NH + h] / (s[dst * NH + h] + 1e-16f);
    if (MEAN) alpha *= 0.5f;
    const float4 hv = *reinterpret_cast<const float4*>(&Hm[(src * NH + h) * C + cq]);
    float* op = MEAN ? &out[dst * C + cq] : &out[(dst * NH + h) * C + cq];
    atomicAdd(op + 0, alpha * hv.x);
    atomicAdd(op + 1, alpha * hv.y);
    atomicAdd(op + 2, alpha * hv.z);
    atomicAdd(op + 3, alpha * hv.w);
}

// ---------------- launch ----------------
extern "C" void kernel_launch(void* const* d_in, const int* in_sizes, int n_in,
                              void* d_out, int out_size, void* d_ws, size_t ws_size,
                              hipStream_t stream) {
    const float* x   = (const float*)d_in[0];
    const int*   ei  = (const int*)d_in[1];
    const float* W1  = (const float*)d_in[2];
    const float* as1 = (const float*)d_in[3];
    const float* ad1 = (const float*)d_in[4];
    const float* b1  = (const float*)d_in[5];
    const float* W2  = (const float*)d_in[6];
    const float* as2 = (const float*)d_in[7];
    const float* ad2 = (const float*)d_in[8];
    const float* b2  = (const float*)d_in[9];
    float* out = (float*)d_out;

    float* ws = (float*)d_ws;
    size_t off = 0;
    float* h1    = ws + off; off += (size_t)NN * FIN;   // [N,128]; later aliased as h2 [N,64]
    float* out1  = ws + off; off += (size_t)NN * FIN;   // [N,128] layer1 pre-bias acc
    float* asrc1 = ws + off; off += (size_t)NN * NH;
    float* adst1 = ws + off; off += (size_t)NN * NH;
    float* m1    = ws + off; off += (size_t)NN * NH;
    float* s1    = ws + off; off += (size_t)NN * NH;
    float* asrc2 = ws + off; off += (size_t)NN * NH;
    float* adst2 = ws + off; off += (size_t)NN * NH;
    float* m2    = ws + off; off += (size_t)NN * NH;
    float* s2    = ws + off; off += (size_t)NN * NH;
    float* ebuf  = ws + off; off += (size_t)NEDGE * NH; // shared across layers
    float* h2 = h1;                                      // alias: h1 dead before gemm2

    const int B = 256;

    // ---- layer 1 ----
    init_layer1<<<2048, B, 0, stream>>>(m1, s1, out1);
    gemm_k128<128, false><<<(NN + 31) / 32, B, 0, stream>>>(x, W1, nullptr, h1, NN);
    attdot<C1><<<(NN * NH + B - 1) / B, B, 0, stream>>>(h1, as1, ad1, asrc1, adst1);
    edge_max<<<(NEDGE + B - 1) / B, B, 0, stream>>>(ei, asrc1, adst1, ebuf, m1);
    edge_exp<<<(NEDGE + B - 1) / B, B, 0, stream>>>(ei, ebuf, m1, s1);
    edge_aggr<C1, false><<<((size_t)NEDGE * 32 + B - 1) / B, B, 0, stream>>>(ei, ebuf, s1, h1, out1);

    // ---- layer 2 ----
    init_layer2<<<2048, B, 0, stream>>>(m2, s2, out, b2);
    gemm_k128<64, true><<<(NN + 63) / 64, B, 0, stream>>>(out1, W2, b1, h2, NN);
    attdot<C2><<<(NN * NH + B - 1) / B, B, 0, stream>>>(h2, as2, ad2, asrc2, adst2);
    edge_max<<<(NEDGE + B - 1) / B, B, 0, stream>>>(ei, asrc2, adst2, ebuf, m2);
    edge_exp<<<(NEDGE + B - 1) / B, B, 0, stream>>>(ei, ebuf, m2, s2);
    edge_aggr<C2, true><<<((size_t)NEDGE * 16 + B - 1) / B, B, 0, stream>>>(ei, ebuf, s2, h2, out);
}

// Round 2
// 455.959 us; speedup vs baseline: 5.8366x; 5.8366x over previous
//
#include <hip/hip_runtime.h>
#include <hip/hip_bf16.h>

// Problem constants (fixed by the reference)
#define NN 50000
#define FIN 128
#define NH 2
#define C1 64
#define C2 32
#define NE 800000
#define NEG 0.2f

__device__ __forceinline__ float lrelu(float v) { return v > 0.0f ? v : NEG * v; }

// ---------------- CSR build ----------------
__global__ void zero_ints(int* __restrict__ a, int n) {
    for (int i = blockIdx.x * blockDim.x + threadIdx.x; i < n;
         i += gridDim.x * blockDim.x) a[i] = 0;
}

__global__ void hist_dst(const int* __restrict__ ei, int* __restrict__ deg) {
    const int i = blockIdx.x * blockDim.x + threadIdx.x;
    if (i >= NE) return;
    atomicAdd(&deg[ei[NE + i]], 1);
}

// block-wise Hillis-Steele scan: offs = exclusive-within-block, bsum = block total
__global__ void scan_blocks(const int* __restrict__ deg, int* __restrict__ offs,
                            int* __restrict__ bsum) {
    __shared__ int sm[256];
    const int t = threadIdx.x;
    const int i = blockIdx.x * 256 + t;
    const int v = (i < NN) ? deg[i] : 0;
    sm[t] = v;
    __syncthreads();
    int x = v;
    #pragma unroll
    for (int d = 1; d < 256; d <<= 1) {
        const int y = (t >= d) ? sm[t - d] : 0;
        __syncthreads();
        x += y; sm[t] = x;
        __syncthreads();
    }
    if (i < NN) offs[i] = x - v;            // exclusive prefix within block
    if (t == 255) bsum[blockIdx.x] = x;     // block total
}

__global__ void scan_bsums(int* __restrict__ bsum, int nb) {  // single block of 256
    __shared__ int sm[256];
    const int t = threadIdx.x;
    const int v = (t < nb) ? bsum[t] : 0;
    sm[t] = v;
    __syncthreads();
    int x = v;
    #pragma unroll
    for (int d = 1; d < 256; d <<= 1) {
        const int y = (t >= d) ? sm[t - d] : 0;
        __syncthreads();
        x += y; sm[t] = x;
        __syncthreads();
    }
    if (t < nb) bsum[t] = x - v;            // exclusive
}

__global__ void scan_add(int* __restrict__ offs, const int* __restrict__ bsum) {
    const int i = blockIdx.x * 256 + threadIdx.x;
    if (i < NN) offs[i] += bsum[blockIdx.x];
}

__global__ void csr_scatter(const int* __restrict__ ei, const int* __restrict__ offs,
                            int* __restrict__ fill, int* __restrict__ esrc) {
    const int i = blockIdx.x * blockDim.x + threadIdx.x;
    if (i >= NE) return;
    const int src = ei[i], dst = ei[NE + i];
    const int pos = offs[dst] + atomicAdd(&fill[dst], 1);
    esrc[pos] = src;
}

// ---------------- GEMM (K=128 fixed), optional fused relu(x+bias) on load ----
template<int BN, bool RELU_BIAS>
__global__ __launch_bounds__(256) void gemm_k128(const float* __restrict__ X,
                                                 const float* __restrict__ Wm,
                                                 const float* __restrict__ bias,
                                                 float* __restrict__ Y, int M) {
    constexpr int GROUPS = BN / 16;      // 8 (BN=128) or 4 (BN=64)
    constexpr int BM = 256 / GROUPS;     // 32 or 64
    __shared__ __align__(16) float Xs[BM][33];
    __shared__ __align__(16) float Ws[32][BN];

    const int tid = threadIdx.x;
    const int r  = tid / GROUPS;
    const int c0 = (tid % GROUPS) * 16;
    const int rowBase = blockIdx.x * BM;

    float4 acc0 = {0,0,0,0}, acc1 = {0,0,0,0}, acc2 = {0,0,0,0}, acc3 = {0,0,0,0};

    for (int kk = 0; kk < 4; ++kk) {
        constexpr int XV = BM * 8;   // float4 count
        #pragma unroll
        for (int i = tid; i < XV; i += 256) {
            const int xr = i >> 3, xc = (i & 7) * 4;
            const int grow = rowBase + xr;
            float4 v = {0,0,0,0};
            if (grow < M) {
                v = *reinterpret_cast<const float4*>(&X[grow * FIN + kk * 32 + xc]);
                if (RELU_BIAS) {
                    const float4 b = *reinterpret_cast<const float4*>(&bias[kk * 32 + xc]);
                    v.x = fmaxf(v.x + b.x, 0.0f);
                    v.y = fmaxf(v.y + b.y, 0.0f);
                    v.z = fmaxf(v.z + b.z, 0.0f);
                    v.w = fmaxf(v.w + b.w, 0.0f);
                }
            }
            Xs[xr][xc] = v.x; Xs[xr][xc+1] = v.y; Xs[xr][xc+2] = v.z; Xs[xr][xc+3] = v.w;
        }
        constexpr int WV = 32 * BN / 4;
        #pragma unroll
        for (int i = tid; i < WV; i += 256) {
            const int wr = i / (BN / 4), wc = (i % (BN / 4)) * 4;
            *reinterpret_cast<float4*>(&Ws[wr][wc]) =
                *reinterpret_cast<const float4*>(&Wm[(kk * 32 + wr) * BN + wc]);
        }
        __syncthreads();
        #pragma unroll
        for (int k = 0; k < 32; ++k) {
            const float xv = Xs[r][k];
            const float4* wrow = reinterpret_cast<const float4*>(&Ws[k][c0]);
            const float4 w0 = wrow[0], w1 = wrow[1], w2 = wrow[2], w3 = wrow[3];
            acc0.x += xv * w0.x; acc0.y += xv * w0.y; acc0.z += xv * w0.z; acc0.w += xv * w0.w;
            acc1.x += xv * w1.x; acc1.y += xv * w1.y; acc1.z += xv * w1.z; acc1.w += xv * w1.w;
            acc2.x += xv * w2.x; acc2.y += xv * w2.y; acc2.z += xv * w2.z; acc2.w += xv * w2.w;
            acc3.x += xv * w3.x; acc3.y += xv * w3.y; acc3.z += xv * w3.z; acc3.w += xv * w3.w;
        }
        __syncthreads();
    }
    const int grow = rowBase + r;
    if (grow < M) {
        float4* yp = reinterpret_cast<float4*>(&Y[grow * BN + c0]);
        yp[0] = acc0; yp[1] = acc1; yp[2] = acc2; yp[3] = acc3;
    }
}

// ---------------- attention dot products: a_src/a_dst [N,H] ----------------
template<int C>
__global__ void attdot(const float* __restrict__ Hm,
                       const float* __restrict__ att_src,
                       const float* __restrict__ att_dst,
                       float* __restrict__ asrc, float* __restrict__ adst) {
    const int i = blockIdx.x * blockDim.x + threadIdx.x;   // over N*H
    if (i >= NN * NH) return;
    const int n = i / NH, h = i % NH;
    const float* hp = Hm + (n * NH + h) * C;
    const float* as = att_src + h * C;
    const float* ad = att_dst + h * C;
    float s1 = 0.0f, s2 = 0.0f;
    #pragma unroll
    for (int c = 0; c < C; c += 4) {
        const float4 hv = *reinterpret_cast<const float4*>(hp + c);
        const float4 a1 = *reinterpret_cast<const float4*>(as + c);
        const float4 a2 = *reinterpret_cast<const float4*>(ad + c);
        s1 += hv.x * a1.x + hv.y * a1.y + hv.z * a1.z + hv.w * a1.w;
        s2 += hv.x * a2.x + hv.y * a2.y + hv.z * a2.z + hv.w * a2.w;
    }
    asrc[i] = s1; adst[i] = s2;
}

// ---------------- fused per-dst softmax + aggregation (layer 1) ----------------
// one wave per dst; lane owns channel `lane` of head0 and head1. H layout [N, 128].
__global__ __launch_bounds__(256) void gat_dst1(const int* __restrict__ esrc,
                                                const int* __restrict__ offs,
                                                const float* __restrict__ H,
                                                const float* __restrict__ asrc,
                                                const float* __restrict__ adst,
                                                float* __restrict__ out) {
    const int wid  = (blockIdx.x * blockDim.x + threadIdx.x) >> 6;
    const int lane = threadIdx.x & 63;
    if (wid >= NN) return;
    const int dst = wid;
    const int beg = offs[dst];
    const int end = (dst == NN - 1) ? NE : offs[dst + 1];
    const float2 ad = *reinterpret_cast<const float2*>(&adst[dst * 2]);

    // self-loop seeds the online softmax (every dst has one)
    float m0, l0, m1, l1, acc0, acc1;
    {
        const float2 as = *reinterpret_cast<const float2*>(&asrc[dst * 2]);
        m0 = lrelu(as.x + ad.x); l0 = 1.0f;
        m1 = lrelu(as.y + ad.y); l1 = 1.0f;
        acc0 = H[dst * 128 + lane];
        acc1 = H[dst * 128 + 64 + lane];
    }
    for (int k = beg; k < end; ++k) {
        const int src = esrc[k];
        const float2 as = *reinterpret_cast<const float2*>(&asrc[src * 2]);
        const float e0 = lrelu(as.x + ad.x);
        const float e1 = lrelu(as.y + ad.y);
        const float h0 = H[src * 128 + lane];
        const float h1 = H[src * 128 + 64 + lane];
        float nm = fmaxf(m0, e0);
        float sc = __expf(m0 - nm), p = __expf(e0 - nm);
        l0 = l0 * sc + p; acc0 = acc0 * sc + p * h0; m0 = nm;
        nm = fmaxf(m1, e1);
        sc = __expf(m1 - nm); p = __expf(e1 - nm);
        l1 = l1 * sc + p; acc1 = acc1 * sc + p * h1; m1 = nm;
    }
    out[dst * 128 + lane]      = acc0 / (l0 + 1e-16f);
    out[dst * 128 + 64 + lane] = acc1 / (l1 + 1e-16f);
}

// ---------------- fused per-dst softmax + aggregation + head-mean (layer 2) ----
// one wave per dst; lane owns (head = lane>>5, chan = lane&31). H layout [N, 64].
__global__ __launch_bounds__(256) void gat_dst2(const int* __restrict__ esrc,
                                                const int* __restrict__ offs,
                                                const float* __restrict__ H,
                                                const float* __restrict__ asrc,
                                                const float* __restrict__ adst,
                                                const float* __restrict__ bias,
                                                float* __restrict__ out) {
    const int wid  = (blockIdx.x * blockDim.x + threadIdx.x) >> 6;
    const int lane = threadIdx.x & 63;
    if (wid >= NN) return;
    const int dst = wid;
    const int h   = lane >> 5;
    const int beg = offs[dst];
    const int end = (dst == NN - 1) ? NE : offs[dst + 1];
    const float adh = adst[dst * 2 + h];

    float m, l, acc;
    {
        const float ash = asrc[dst * 2 + h];
        m = lrelu(ash + adh); l = 1.0f;
        acc = H[dst * 64 + lane];
    }
    for (int k = beg; k < end; ++k) {
        const int src = esrc[k];
        const float ash = asrc[src * 2 + h];
        const float e = lrelu(ash + adh);
        const float hv = H[src * 64 + lane];
        const float nm = fmaxf(m, e);
        const float sc = __expf(m - nm), p = __expf(e - nm);
        l = l * sc + p; acc = acc * sc + p * hv; m = nm;
    }
    float r = acc / (l + 1e-16f);
    r += __shfl_xor(r, 32);               // combine heads (width = wave = 64)
    if (lane < 32) out[dst * 32 + lane] = 0.5f * r + bias[lane];
}

// ---------------- launch ----------------
extern "C" void kernel_launch(void* const* d_in, const int* in_sizes, int n_in,
                              void* d_out, int out_size, void* d_ws, size_t ws_size,
                              hipStream_t stream) {
    const float* x   = (const float*)d_in[0];
    const int*   ei  = (const int*)d_in[1];
    const float* W1  = (const float*)d_in[2];
    const float* as1 = (const float*)d_in[3];
    const float* ad1 = (const float*)d_in[4];
    const float* b1  = (const float*)d_in[5];
    const float* W2  = (const float*)d_in[6];
    const float* as2 = (const float*)d_in[7];
    const float* ad2 = (const float*)d_in[8];
    const float* b2  = (const float*)d_in[9];
    float* out = (float*)d_out;

    float* ws = (float*)d_ws;
    size_t off = 0;
    float* h1    = ws + off; off += (size_t)NN * FIN;   // [N,128]; reused as h2 [N,64]
    float* out1  = ws + off; off += (size_t)NN * FIN;   // [N,128] layer1 output
    float* asrc1 = ws + off; off += (size_t)NN * NH;
    float* adst1 = ws + off; off += (size_t)NN * NH;
    float* asrc2 = ws + off; off += (size_t)NN * NH;
    float* adst2 = ws + off; off += (size_t)NN * NH;
    int* ibase = (int*)(ws + off);
    int* deg   = ibase;                 // [NN]
    int* offs  = ibase + NN;            // [NN]
    int* fill  = ibase + 2 * NN;        // [NN]
    int* bsum  = ibase + 3 * NN;        // [256]
    int* esrc  = ibase + 3 * NN + 256;  // [NE]
    float* h2 = h1;                     // alias: h1 dead before gemm2 writes h2

    const int B = 256;
    constexpr int NB_SCAN = (NN + 255) / 256;   // 196

    // ---- CSR build (shared by both layers) ----
    zero_ints<<<128, B, 0, stream>>>(deg, 2 * NN);               // deg + offs? no: deg[NN] then offs... zero deg and fill
    // note: zero deg and fill (they are adjacent? deg at 0, fill at 2*NN) — do both explicitly
    zero_ints<<<128, B, 0, stream>>>(fill, NN);
    hist_dst<<<(NE + B - 1) / B, B, 0, stream>>>(ei, deg);
    scan_blocks<<<NB_SCAN, 256, 0, stream>>>(deg, offs, bsum);
    scan_bsums<<<1, 256, 0, stream>>>(bsum, NB_SCAN);
    scan_add<<<NB_SCAN, 256, 0, stream>>>(offs, bsum);
    csr_scatter<<<(NE + B - 1) / B, B, 0, stream>>>(ei, offs, fill, esrc);

    // ---- layer 1 ----
    gemm_k128<128, false><<<(NN + 31) / 32, B, 0, stream>>>(x, W1, nullptr, h1, NN);
    attdot<C1><<<(NN * NH + B - 1) / B, B, 0, stream>>>(h1, as1, ad1, asrc1, adst1);
    gat_dst1<<<(NN * 64 + B - 1) / B, B, 0, stream>>>(esrc, offs, h1, asrc1, adst1, out1);

    // ---- layer 2 ----
    gemm_k128<64, true><<<(NN + 63) / 64, B, 0, stream>>>(out1, W2, b1, h2, NN);
    attdot<C2><<<(NN * NH + B - 1) / B, B, 0, stream>>>(h2, as2, ad2, asrc2, adst2);
    gat_dst2<<<(NN * 64 + B - 1) / B, B, 0, stream>>>(esrc, offs, h2, asrc2, adst2, b2, out);
}

// Round 3
// 381.858 us; speedup vs baseline: 6.9692x; 1.1941x over previous
//
#include <hip/hip_runtime.h>
#include <hip/hip_bf16.h>

// Problem constants (fixed by the reference)
#define NN 50000
#define FIN 128
#define NH 2
#define C1 64
#define C2 32
#define NE 800000
#define NEG 0.2f

__device__ __forceinline__ float lrelu(float v) { return v > 0.0f ? v : NEG * v; }
__device__ __forceinline__ float dot4(float4 a, float4 b) {
    return a.x * b.x + a.y * b.y + a.z * b.z + a.w * b.w;
}

// ---------------- CSR build ----------------
__global__ void zero_ints(int* __restrict__ a, int n) {
    for (int i = blockIdx.x * blockDim.x + threadIdx.x; i < n;
         i += gridDim.x * blockDim.x) a[i] = 0;
}

__global__ void hist_dst(const int* __restrict__ ei, int* __restrict__ deg) {
    const int i = blockIdx.x * blockDim.x + threadIdx.x;
    if (i >= NE) return;
    atomicAdd(&deg[ei[NE + i]], 1);
}

__global__ void scan_blocks(const int* __restrict__ deg, int* __restrict__ offs,
                            int* __restrict__ bsum) {
    __shared__ int sm[256];
    const int t = threadIdx.x;
    const int i = blockIdx.x * 256 + t;
    const int v = (i < NN) ? deg[i] : 0;
    sm[t] = v;
    __syncthreads();
    int x = v;
    #pragma unroll
    for (int d = 1; d < 256; d <<= 1) {
        const int y = (t >= d) ? sm[t - d] : 0;
        __syncthreads();
        x += y; sm[t] = x;
        __syncthreads();
    }
    if (i < NN) offs[i] = x - v;
    if (t == 255) bsum[blockIdx.x] = x;
}

__global__ void scan_bsums(int* __restrict__ bsum, int nb) {
    __shared__ int sm[256];
    const int t = threadIdx.x;
    const int v = (t < nb) ? bsum[t] : 0;
    sm[t] = v;
    __syncthreads();
    int x = v;
    #pragma unroll
    for (int d = 1; d < 256; d <<= 1) {
        const int y = (t >= d) ? sm[t - d] : 0;
        __syncthreads();
        x += y; sm[t] = x;
        __syncthreads();
    }
    if (t < nb) bsum[t] = x - v;
}

__global__ void scan_add(int* __restrict__ offs, const int* __restrict__ bsum) {
    const int i = blockIdx.x * 256 + threadIdx.x;
    if (i < NN) offs[i] += bsum[blockIdx.x];
}

__global__ void csr_scatter(const int* __restrict__ ei, const int* __restrict__ offs,
                            int* __restrict__ fill, int* __restrict__ esrc) {
    const int i = blockIdx.x * blockDim.x + threadIdx.x;
    if (i >= NE) return;
    const int src = ei[i], dst = ei[NE + i];
    const int pos = offs[dst] + atomicAdd(&fill[dst], 1);
    esrc[pos] = src;
}

// ------- GEMM (K=128) + fused relu(x+bias) on load + fused attention dots -----
// BN=128: att vector layout [2,64] = 128 floats matches columns exactly.
// BN=64:  att vector layout [2,32] = 64 floats matches columns exactly.
template<int BN, bool RELU_BIAS>
__global__ __launch_bounds__(256) void gemm_k128(const float* __restrict__ X,
                                                 const float* __restrict__ Wm,
                                                 const float* __restrict__ bias,
                                                 const float* __restrict__ attS,
                                                 const float* __restrict__ attD,
                                                 float* __restrict__ Y,
                                                 float* __restrict__ asrcO,
                                                 float* __restrict__ adstO, int M) {
    constexpr int GROUPS = BN / 16;      // 8 (BN=128) or 4 (BN=64)
    constexpr int BM = 256 / GROUPS;     // 32 or 64
    constexpr int HEADG = GROUPS / 2;    // lanes per head within a row
    __shared__ __align__(16) float Xs[BM][33];
    __shared__ __align__(16) float Ws[32][BN];

    const int tid = threadIdx.x;
    const int r  = tid / GROUPS;
    const int g  = tid % GROUPS;
    const int c0 = g * 16;
    const int rowBase = blockIdx.x * BM;

    float4 acc0 = {0,0,0,0}, acc1 = {0,0,0,0}, acc2 = {0,0,0,0}, acc3 = {0,0,0,0};

    for (int kk = 0; kk < 4; ++kk) {
        constexpr int XV = BM * 8;
        #pragma unroll
        for (int i = tid; i < XV; i += 256) {
            const int xr = i >> 3, xc = (i & 7) * 4;
            const int grow = rowBase + xr;
            float4 v = {0,0,0,0};
            if (grow < M) {
                v = *reinterpret_cast<const float4*>(&X[grow * FIN + kk * 32 + xc]);
                if (RELU_BIAS) {
                    const float4 b = *reinterpret_cast<const float4*>(&bias[kk * 32 + xc]);
                    v.x = fmaxf(v.x + b.x, 0.0f);
                    v.y = fmaxf(v.y + b.y, 0.0f);
                    v.z = fmaxf(v.z + b.z, 0.0f);
                    v.w = fmaxf(v.w + b.w, 0.0f);
                }
            }
            Xs[xr][xc] = v.x; Xs[xr][xc+1] = v.y; Xs[xr][xc+2] = v.z; Xs[xr][xc+3] = v.w;
        }
        constexpr int WV = 32 * BN / 4;
        #pragma unroll
        for (int i = tid; i < WV; i += 256) {
            const int wr = i / (BN / 4), wc = (i % (BN / 4)) * 4;
            *reinterpret_cast<float4*>(&Ws[wr][wc]) =
                *reinterpret_cast<const float4*>(&Wm[(kk * 32 + wr) * BN + wc]);
        }
        __syncthreads();
        #pragma unroll
        for (int k = 0; k < 32; ++k) {
            const float xv = Xs[r][k];
            const float4* wrow = reinterpret_cast<const float4*>(&Ws[k][c0]);
            const float4 w0 = wrow[0], w1 = wrow[1], w2 = wrow[2], w3 = wrow[3];
            acc0.x += xv * w0.x; acc0.y += xv * w0.y; acc0.z += xv * w0.z; acc0.w += xv * w0.w;
            acc1.x += xv * w1.x; acc1.y += xv * w1.y; acc1.z += xv * w1.z; acc1.w += xv * w1.w;
            acc2.x += xv * w2.x; acc2.y += xv * w2.y; acc2.z += xv * w2.z; acc2.w += xv * w2.w;
            acc3.x += xv * w3.x; acc3.y += xv * w3.y; acc3.z += xv * w3.z; acc3.w += xv * w3.w;
        }
        __syncthreads();
    }
    const int grow = rowBase + r;
    if (grow < M) {
        float4* yp = reinterpret_cast<float4*>(&Y[grow * BN + c0]);
        yp[0] = acc0; yp[1] = acc1; yp[2] = acc2; yp[3] = acc3;
    }
    // fused attention dot products (att vectors are L2-hot, 256/512 B)
    const float4* avs = reinterpret_cast<const float4*>(&attS[c0]);
    const float4* avd = reinterpret_cast<const float4*>(&attD[c0]);
    float ps = dot4(acc0, avs[0]) + dot4(acc1, avs[1]) + dot4(acc2, avs[2]) + dot4(acc3, avs[3]);
    float pd = dot4(acc0, avd[0]) + dot4(acc1, avd[1]) + dot4(acc2, avd[2]) + dot4(acc3, avd[3]);
    #pragma unroll
    for (int d = 1; d < HEADG; d <<= 1) {
        ps += __shfl_xor(ps, d);
        pd += __shfl_xor(pd, d);
    }
    if ((g & (HEADG - 1)) == 0 && grow < M) {
        const int head = g / HEADG;
        asrcO[grow * 2 + head] = ps;
        adstO[grow * 2 + head] = pd;
    }
}

// ---------------- fused per-dst softmax + aggregation (layer 1) ----------------
// one wave per dst; lane owns channels {2*lane, 2*lane+1} (same head, h = lane>>5).
// unroll-by-2 with two independent online-softmax states merged at the end.
__global__ __launch_bounds__(256) void gat_dst1(const int* __restrict__ esrc,
                                                const int* __restrict__ offs,
                                                const float* __restrict__ H,
                                                const float* __restrict__ asrc,
                                                const float* __restrict__ adst,
                                                float* __restrict__ out) {
    const int wid  = (blockIdx.x * blockDim.x + threadIdx.x) >> 6;
    const int lane = threadIdx.x & 63;
    if (wid >= NN) return;
    const int dst = wid;
    const int h   = lane >> 5;
    const int beg = offs[dst];
    const int end = (dst == NN - 1) ? NE : offs[dst + 1];
    const float adh = adst[dst * 2 + h];

    // state A seeded with the self-loop; state B empty (m=-inf -> exp()=0)
    float mA, lA;
    float2 accA;
    {
        mA = lrelu(asrc[dst * 2 + h] + adh);
        lA = 1.0f;
        accA = *reinterpret_cast<const float2*>(&H[dst * 128 + lane * 2]);
    }
    float mB = -INFINITY, lB = 0.0f;
    float2 accB = {0.0f, 0.0f};

    int k = beg;
    for (; k + 1 < end; k += 2) {
        const int sA = esrc[k], sB = esrc[k + 1];
        const float2 hA = *reinterpret_cast<const float2*>(&H[sA * 128 + lane * 2]);
        const float2 hB = *reinterpret_cast<const float2*>(&H[sB * 128 + lane * 2]);
        const float aA = asrc[sA * 2 + h];
        const float aB = asrc[sB * 2 + h];
        {
            const float e = lrelu(aA + adh);
            const float nm = fmaxf(mA, e);
            const float sc = __expf(mA - nm), p = __expf(e - nm);
            lA = lA * sc + p;
            accA.x = accA.x * sc + p * hA.x;
            accA.y = accA.y * sc + p * hA.y;
            mA = nm;
        }
        {
            const float e = lrelu(aB + adh);
            const float nm = fmaxf(mB, e);
            const float sc = __expf(mB - nm), p = __expf(e - nm);
            lB = lB * sc + p;
            accB.x = accB.x * sc + p * hB.x;
            accB.y = accB.y * sc + p * hB.y;
            mB = nm;
        }
    }
    if (k < end) {
        const int sA = esrc[k];
        const float2 hA = *reinterpret_cast<const float2*>(&H[sA * 128 + lane * 2]);
        const float aA = asrc[sA * 2 + h];
        const float e = lrelu(aA + adh);
        const float nm = fmaxf(mA, e);
        const float sc = __expf(mA - nm), p = __expf(e - nm);
        lA = lA * sc + p;
        accA.x = accA.x * sc + p * hA.x;
        accA.y = accA.y * sc + p * hA.y;
        mA = nm;
    }
    // merge B into A (exact)
    {
        const float nm = fmaxf(mA, mB);
        const float eA = __expf(mA - nm), eB = __expf(mB - nm);
        lA = lA * eA + lB * eB;
        accA.x = accA.x * eA + accB.x * eB;
        accA.y = accA.y * eA + accB.y * eB;
    }
    const float inv = 1.0f / (lA + 1e-16f);
    float2 res;
    res.x = accA.x * inv;
    res.y = accA.y * inv;
    *reinterpret_cast<float2*>(&out[dst * 128 + lane * 2]) = res;
}

// ---------------- fused per-dst softmax + aggregation + head-mean (layer 2) ----
// one wave per dst; lane owns (head = lane>>5, chan = lane&31). H layout [N, 64].
__global__ __launch_bounds__(256) void gat_dst2(const int* __restrict__ esrc,
                                                const int* __restrict__ offs,
                                                const float* __restrict__ H,
                                                const float* __restrict__ asrc,
                                                const float* __restrict__ adst,
                                                const float* __restrict__ bias,
                                                float* __restrict__ out) {
    const int wid  = (blockIdx.x * blockDim.x + threadIdx.x) >> 6;
    const int lane = threadIdx.x & 63;
    if (wid >= NN) return;
    const int dst = wid;
    const int h   = lane >> 5;
    const int beg = offs[dst];
    const int end = (dst == NN - 1) ? NE : offs[dst + 1];
    const float adh = adst[dst * 2 + h];

    float mA, lA, accA;
    {
        mA = lrelu(asrc[dst * 2 + h] + adh);
        lA = 1.0f;
        accA = H[dst * 64 + lane];
    }
    float mB = -INFINITY, lB = 0.0f, accB = 0.0f;

    int k = beg;
    for (; k + 1 < end; k += 2) {
        const int sA = esrc[k], sB = esrc[k + 1];
        const float hA = H[sA * 64 + lane];
        const float hB = H[sB * 64 + lane];
        const float aA = asrc[sA * 2 + h];
        const float aB = asrc[sB * 2 + h];
        {
            const float e = lrelu(aA + adh);
            const float nm = fmaxf(mA, e);
            const float sc = __expf(mA - nm), p = __expf(e - nm);
            lA = lA * sc + p; accA = accA * sc + p * hA; mA = nm;
        }
        {
            const float e = lrelu(aB + adh);
            const float nm = fmaxf(mB, e);
            const float sc = __expf(mB - nm), p = __expf(e - nm);
            lB = lB * sc + p; accB = accB * sc + p * hB; mB = nm;
        }
    }
    if (k < end) {
        const int sA = esrc[k];
        const float hA = H[sA * 64 + lane];
        const float aA = asrc[sA * 2 + h];
        const float e = lrelu(aA + adh);
        const float nm = fmaxf(mA, e);
        const float sc = __expf(mA - nm), p = __expf(e - nm);
        lA = lA * sc + p; accA = accA * sc + p * hA; mA = nm;
    }
    {
        const float nm = fmaxf(mA, mB);
        const float eA = __expf(mA - nm), eB = __expf(mB - nm);
        lA = lA * eA + lB * eB;
        accA = accA * eA + accB * eB;
    }
    float r = accA / (lA + 1e-16f);
    r += __shfl_xor(r, 32);               // combine heads
    if (lane < 32) out[dst * 32 + lane] = 0.5f * r + bias[lane];
}

// ---------------- launch ----------------
extern "C" void kernel_launch(void* const* d_in, const int* in_sizes, int n_in,
                              void* d_out, int out_size, void* d_ws, size_t ws_size,
                              hipStream_t stream) {
    const float* x   = (const float*)d_in[0];
    const int*   ei  = (const int*)d_in[1];
    const float* W1  = (const float*)d_in[2];
    const float* as1 = (const float*)d_in[3];
    const float* ad1 = (const float*)d_in[4];
    const float* b1  = (const float*)d_in[5];
    const float* W2  = (const float*)d_in[6];
    const float* as2 = (const float*)d_in[7];
    const float* ad2 = (const float*)d_in[8];
    const float* b2  = (const float*)d_in[9];
    float* out = (float*)d_out;

    float* ws = (float*)d_ws;
    size_t off = 0;
    float* h1    = ws + off; off += (size_t)NN * FIN;   // [N,128]; reused as h2 [N,64]
    float* out1  = ws + off; off += (size_t)NN * FIN;   // [N,128] layer1 output
    float* asrc1 = ws + off; off += (size_t)NN * NH;
    float* adst1 = ws + off; off += (size_t)NN * NH;
    float* asrc2 = ws + off; off += (size_t)NN * NH;
    float* adst2 = ws + off; off += (size_t)NN * NH;
    int* ibase = (int*)(ws + off);
    int* deg   = ibase;                 // [NN]
    int* offs  = ibase + NN;            // [NN]
    int* fill  = ibase + 2 * NN;        // [NN]
    int* bsum  = ibase + 3 * NN;        // [256]
    int* esrc  = ibase + 3 * NN + 256;  // [NE]
    float* h2 = h1;                     // alias: h1 dead before gemm2 writes h2

    const int B = 256;
    constexpr int NB_SCAN = (NN + 255) / 256;   // 196

    // ---- CSR build (shared by both layers) ----
    zero_ints<<<64, B, 0, stream>>>(deg, NN);
    zero_ints<<<64, B, 0, stream>>>(fill, NN);
    hist_dst<<<(NE + B - 1) / B, B, 0, stream>>>(ei, deg);
    scan_blocks<<<NB_SCAN, 256, 0, stream>>>(deg, offs, bsum);
    scan_bsums<<<1, 256, 0, stream>>>(bsum, NB_SCAN);
    scan_add<<<NB_SCAN, 256, 0, stream>>>(offs, bsum);
    csr_scatter<<<(NE + B - 1) / B, B, 0, stream>>>(ei, offs, fill, esrc);

    // ---- layer 1 ----
    gemm_k128<128, false><<<(NN + 31) / 32, B, 0, stream>>>(
        x, W1, nullptr, as1, ad1, h1, asrc1, adst1, NN);
    gat_dst1<<<(NN * 64 + B - 1) / B, B, 0, stream>>>(esrc, offs, h1, asrc1, adst1, out1);

    // ---- layer 2 ----
    gemm_k128<64, true><<<(NN + 63) / 64, B, 0, stream>>>(
        out1, W2, b1, as2, ad2, h2, asrc2, adst2, NN);
    gat_dst2<<<(NN * 64 + B - 1) / B, B, 0, stream>>>(esrc, offs, h2, asrc2, adst2, b2, out);
}

// Round 4
// 378.378 us; speedup vs baseline: 7.0333x; 1.0092x over previous
//
#include <hip/hip_runtime.h>
#include <hip/hip_bf16.h>

// Problem constants (fixed by the reference)
#define NN 50000
#define FIN 128
#define NH 2
#define C1 64
#define C2 32
#define NE 800000
#define NEG 0.2f

__device__ __forceinline__ float lrelu(float v) { return v > 0.0f ? v : NEG * v; }
__device__ __forceinline__ float dot4(float4 a, float4 b) {
    return a.x * b.x + a.y * b.y + a.z * b.z + a.w * b.w;
}

// ---------------- CSR build ----------------
__global__ void zero_ints(int* __restrict__ a, int n) {
    for (int i = blockIdx.x * blockDim.x + threadIdx.x; i < n;
         i += gridDim.x * blockDim.x) a[i] = 0;
}

__global__ void hist_dst(const int* __restrict__ ei, int* __restrict__ deg) {
    const int i = blockIdx.x * blockDim.x + threadIdx.x;
    if (i >= NE) return;
    atomicAdd(&deg[ei[NE + i]], 1);
}

__global__ void scan_blocks(const int* __restrict__ deg, int* __restrict__ offs,
                            int* __restrict__ bsum) {
    __shared__ int sm[256];
    const int t = threadIdx.x;
    const int i = blockIdx.x * 256 + t;
    const int v = (i < NN) ? deg[i] : 0;
    sm[t] = v;
    __syncthreads();
    int x = v;
    #pragma unroll
    for (int d = 1; d < 256; d <<= 1) {
        const int y = (t >= d) ? sm[t - d] : 0;
        __syncthreads();
        x += y; sm[t] = x;
        __syncthreads();
    }
    if (i < NN) offs[i] = x - v;
    if (t == 255) bsum[blockIdx.x] = x;
}

__global__ void scan_bsums(int* __restrict__ bsum, int nb) {
    __shared__ int sm[256];
    const int t = threadIdx.x;
    const int v = (t < nb) ? bsum[t] : 0;
    sm[t] = v;
    __syncthreads();
    int x = v;
    #pragma unroll
    for (int d = 1; d < 256; d <<= 1) {
        const int y = (t >= d) ? sm[t - d] : 0;
        __syncthreads();
        x += y; sm[t] = x;
        __syncthreads();
    }
    if (t < nb) bsum[t] = x - v;
}

__global__ void scan_add(int* __restrict__ offs, const int* __restrict__ bsum) {
    const int i = blockIdx.x * 256 + threadIdx.x;
    if (i < NN) offs[i] += bsum[blockIdx.x];
}

__global__ void csr_scatter(const int* __restrict__ ei, const int* __restrict__ offs,
                            int* __restrict__ fill, int* __restrict__ esrc) {
    const int i = blockIdx.x * blockDim.x + threadIdx.x;
    if (i >= NE) return;
    const int src = ei[i], dst = ei[NE + i];
    const int pos = offs[dst] + atomicAdd(&fill[dst], 1);
    esrc[pos] = src;
}

// ------- GEMM (K=128) + fused relu(x+bias) on load + fused attention dots -----
// Lane g owns 4 float4 column chunks at stride BN/4: cols g*4 + (BN/4)*j.
// Per ds_read_b128 the GROUPS g-values cover banks g*4..g*4+3 (all distinct);
// lanes with equal g broadcast -> conflict-free (was 8-way on contiguous cols).
// Head split: j in {0,1} -> head0 columns, j in {2,3} -> head1 columns.
template<int BN, bool RELU_BIAS>
__global__ __launch_bounds__(256) void gemm_k128(const float* __restrict__ X,
                                                 const float* __restrict__ Wm,
                                                 const float* __restrict__ bias,
                                                 const float* __restrict__ attS,
                                                 const float* __restrict__ attD,
                                                 float* __restrict__ Y,
                                                 float* __restrict__ asrcO,
                                                 float* __restrict__ adstO, int M) {
    constexpr int GROUPS = BN / 16;      // 8 (BN=128) or 4 (BN=64)
    constexpr int BM = 256 / GROUPS;     // 32 or 64
    constexpr int CS = BN / 4;           // column stride between a lane's chunks
    __shared__ __align__(16) float Xs[BM][33];
    __shared__ __align__(16) float Ws[32][BN];

    const int tid = threadIdx.x;
    const int r  = tid / GROUPS;
    const int g  = tid % GROUPS;
    const int rowBase = blockIdx.x * BM;

    float4 acc0 = {0,0,0,0}, acc1 = {0,0,0,0}, acc2 = {0,0,0,0}, acc3 = {0,0,0,0};

    for (int kk = 0; kk < 4; ++kk) {
        constexpr int XV = BM * 8;
        #pragma unroll
        for (int i = tid; i < XV; i += 256) {
            const int xr = i >> 3, xc = (i & 7) * 4;
            const int grow = rowBase + xr;
            float4 v = {0,0,0,0};
            if (grow < M) {
                v = *reinterpret_cast<const float4*>(&X[grow * FIN + kk * 32 + xc]);
                if (RELU_BIAS) {
                    const float4 b = *reinterpret_cast<const float4*>(&bias[kk * 32 + xc]);
                    v.x = fmaxf(v.x + b.x, 0.0f);
                    v.y = fmaxf(v.y + b.y, 0.0f);
                    v.z = fmaxf(v.z + b.z, 0.0f);
                    v.w = fmaxf(v.w + b.w, 0.0f);
                }
            }
            Xs[xr][xc] = v.x; Xs[xr][xc+1] = v.y; Xs[xr][xc+2] = v.z; Xs[xr][xc+3] = v.w;
        }
        constexpr int WV = 32 * BN / 4;
        #pragma unroll
        for (int i = tid; i < WV; i += 256) {
            const int wr = i / (BN / 4), wc = (i % (BN / 4)) * 4;
            *reinterpret_cast<float4*>(&Ws[wr][wc]) =
                *reinterpret_cast<const float4*>(&Wm[(kk * 32 + wr) * BN + wc]);
        }
        __syncthreads();
        #pragma unroll
        for (int k = 0; k < 32; ++k) {
            const float xv = Xs[r][k];
            const float4 w0 = *reinterpret_cast<const float4*>(&Ws[k][g * 4]);
            const float4 w1 = *reinterpret_cast<const float4*>(&Ws[k][g * 4 + CS]);
            const float4 w2 = *reinterpret_cast<const float4*>(&Ws[k][g * 4 + 2 * CS]);
            const float4 w3 = *reinterpret_cast<const float4*>(&Ws[k][g * 4 + 3 * CS]);
            acc0.x += xv * w0.x; acc0.y += xv * w0.y; acc0.z += xv * w0.z; acc0.w += xv * w0.w;
            acc1.x += xv * w1.x; acc1.y += xv * w1.y; acc1.z += xv * w1.z; acc1.w += xv * w1.w;
            acc2.x += xv * w2.x; acc2.y += xv * w2.y; acc2.z += xv * w2.z; acc2.w += xv * w2.w;
            acc3.x += xv * w3.x; acc3.y += xv * w3.y; acc3.z += xv * w3.z; acc3.w += xv * w3.w;
        }
        __syncthreads();
    }
    const int grow = rowBase + r;
    if (grow < M) {
        float* yrow = &Y[grow * BN + g * 4];
        *reinterpret_cast<float4*>(yrow)          = acc0;
        *reinterpret_cast<float4*>(yrow + CS)     = acc1;
        *reinterpret_cast<float4*>(yrow + 2 * CS) = acc2;
        *reinterpret_cast<float4*>(yrow + 3 * CS) = acc3;
    }
    // fused attention dot products; att vector float4 index = g + GROUPS*j
    const float4* avs = reinterpret_cast<const float4*>(attS);
    const float4* avd = reinterpret_cast<const float4*>(attD);
    float ps0 = dot4(acc0, avs[g])              + dot4(acc1, avs[g + GROUPS]);
    float ps1 = dot4(acc2, avs[g + 2 * GROUPS]) + dot4(acc3, avs[g + 3 * GROUPS]);
    float pd0 = dot4(acc0, avd[g])              + dot4(acc1, avd[g + GROUPS]);
    float pd1 = dot4(acc2, avd[g + 2 * GROUPS]) + dot4(acc3, avd[g + 3 * GROUPS]);
    #pragma unroll
    for (int d = 1; d < GROUPS; d <<= 1) {
        ps0 += __shfl_xor(ps0, d);
        ps1 += __shfl_xor(ps1, d);
        pd0 += __shfl_xor(pd0, d);
        pd1 += __shfl_xor(pd1, d);
    }
    if (g == 0 && grow < M) {
        asrcO[grow * 2]     = ps0;
        asrcO[grow * 2 + 1] = ps1;
        adstO[grow * 2]     = pd0;
        adstO[grow * 2 + 1] = pd1;
    }
}

// ---------------- fused per-dst softmax + aggregation (layer 1) ----------------
__global__ __launch_bounds__(256) void gat_dst1(const int* __restrict__ esrc,
                                                const int* __restrict__ offs,
                                                const float* __restrict__ H,
                                                const float* __restrict__ asrc,
                                                const float* __restrict__ adst,
                                                float* __restrict__ out) {
    const int wid  = (blockIdx.x * blockDim.x + threadIdx.x) >> 6;
    const int lane = threadIdx.x & 63;
    if (wid >= NN) return;
    const int dst = wid;
    const int h   = lane >> 5;
    const int beg = offs[dst];
    const int end = (dst == NN - 1) ? NE : offs[dst + 1];
    const float adh = adst[dst * 2 + h];

    float mA, lA;
    float2 accA;
    {
        mA = lrelu(asrc[dst * 2 + h] + adh);
        lA = 1.0f;
        accA = *reinterpret_cast<const float2*>(&H[dst * 128 + lane * 2]);
    }
    float mB = -INFINITY, lB = 0.0f;
    float2 accB = {0.0f, 0.0f};

    int k = beg;
    for (; k + 1 < end; k += 2) {
        const int sA = esrc[k], sB = esrc[k + 1];
        const float2 hA = *reinterpret_cast<const float2*>(&H[sA * 128 + lane * 2]);
        const float2 hB = *reinterpret_cast<const float2*>(&H[sB * 128 + lane * 2]);
        const float aA = asrc[sA * 2 + h];
        const float aB = asrc[sB * 2 + h];
        {
            const float e = lrelu(aA + adh);
            const float nm = fmaxf(mA, e);
            const float sc = __expf(mA - nm), p = __expf(e - nm);
            lA = lA * sc + p;
            accA.x = accA.x * sc + p * hA.x;
            accA.y = accA.y * sc + p * hA.y;
            mA = nm;
        }
        {
            const float e = lrelu(aB + adh);
            const float nm = fmaxf(mB, e);
            const float sc = __expf(mB - nm), p = __expf(e - nm);
            lB = lB * sc + p;
            accB.x = accB.x * sc + p * hB.x;
            accB.y = accB.y * sc + p * hB.y;
            mB = nm;
        }
    }
    if (k < end) {
        const int sA = esrc[k];
        const float2 hA = *reinterpret_cast<const float2*>(&H[sA * 128 + lane * 2]);
        const float aA = asrc[sA * 2 + h];
        const float e = lrelu(aA + adh);
        const float nm = fmaxf(mA, e);
        const float sc = __expf(mA - nm), p = __expf(e - nm);
        lA = lA * sc + p;
        accA.x = accA.x * sc + p * hA.x;
        accA.y = accA.y * sc + p * hA.y;
        mA = nm;
    }
    {
        const float nm = fmaxf(mA, mB);
        const float eA = __expf(mA - nm), eB = __expf(mB - nm);
        lA = lA * eA + lB * eB;
        accA.x = accA.x * eA + accB.x * eB;
        accA.y = accA.y * eA + accB.y * eB;
    }
    const float inv = 1.0f / (lA + 1e-16f);
    float2 res;
    res.x = accA.x * inv;
    res.y = accA.y * inv;
    *reinterpret_cast<float2*>(&out[dst * 128 + lane * 2]) = res;
}

// ---------------- fused per-dst softmax + aggregation + head-mean (layer 2) ----
__global__ __launch_bounds__(256) void gat_dst2(const int* __restrict__ esrc,
                                                const int* __restrict__ offs,
                                                const float* __restrict__ H,
                                                const float* __restrict__ asrc,
                                                const float* __restrict__ adst,
                                                const float* __restrict__ bias,
                                                float* __restrict__ out) {
    const int wid  = (blockIdx.x * blockDim.x + threadIdx.x) >> 6;
    const int lane = threadIdx.x & 63;
    if (wid >= NN) return;
    const int dst = wid;
    const int h   = lane >> 5;
    const int beg = offs[dst];
    const int end = (dst == NN - 1) ? NE : offs[dst + 1];
    const float adh = adst[dst * 2 + h];

    float mA, lA, accA;
    {
        mA = lrelu(asrc[dst * 2 + h] + adh);
        lA = 1.0f;
        accA = H[dst * 64 + lane];
    }
    float mB = -INFINITY, lB = 0.0f, accB = 0.0f;

    int k = beg;
    for (; k + 1 < end; k += 2) {
        const int sA = esrc[k], sB = esrc[k + 1];
        const float hA = H[sA * 64 + lane];
        const float hB = H[sB * 64 + lane];
        const float aA = asrc[sA * 2 + h];
        const float aB = asrc[sB * 2 + h];
        {
            const float e = lrelu(aA + adh);
            const float nm = fmaxf(mA, e);
            const float sc = __expf(mA - nm), p = __expf(e - nm);
            lA = lA * sc + p; accA = accA * sc + p * hA; mA = nm;
        }
        {
            const float e = lrelu(aB + adh);
            const float nm = fmaxf(mB, e);
            const float sc = __expf(mB - nm), p = __expf(e - nm);
            lB = lB * sc + p; accB = accB * sc + p * hB; mB = nm;
        }
    }
    if (k < end) {
        const int sA = esrc[k];
        const float hA = H[sA * 64 + lane];
        const float aA = asrc[sA * 2 + h];
        const float e = lrelu(aA + adh);
        const float nm = fmaxf(mA, e);
        const float sc = __expf(mA - nm), p = __expf(e - nm);
        lA = lA * sc + p; accA = accA * sc + p * hA; mA = nm;
    }
    {
        const float nm = fmaxf(mA, mB);
        const float eA = __expf(mA - nm), eB = __expf(mB - nm);
        lA = lA * eA + lB * eB;
        accA = accA * eA + accB * eB;
    }
    float r = accA / (lA + 1e-16f);
    r += __shfl_xor(r, 32);               // combine heads
    if (lane < 32) out[dst * 32 + lane] = 0.5f * r + bias[lane];
}

// ---------------- launch ----------------
extern "C" void kernel_launch(void* const* d_in, const int* in_sizes, int n_in,
                              void* d_out, int out_size, void* d_ws, size_t ws_size,
                              hipStream_t stream) {
    const float* x   = (const float*)d_in[0];
    const int*   ei  = (const int*)d_in[1];
    const float* W1  = (const float*)d_in[2];
    const float* as1 = (const float*)d_in[3];
    const float* ad1 = (const float*)d_in[4];
    const float* b1  = (const float*)d_in[5];
    const float* W2  = (const float*)d_in[6];
    const float* as2 = (const float*)d_in[7];
    const float* ad2 = (const float*)d_in[8];
    const float* b2  = (const float*)d_in[9];
    float* out = (float*)d_out;

    float* ws = (float*)d_ws;
    size_t off = 0;
    float* h1    = ws + off; off += (size_t)NN * FIN;   // [N,128]; reused as h2 [N,64]
    float* out1  = ws + off; off += (size_t)NN * FIN;   // [N,128] layer1 output
    float* asrc1 = ws + off; off += (size_t)NN * NH;
    float* adst1 = ws + off; off += (size_t)NN * NH;
    float* asrc2 = ws + off; off += (size_t)NN * NH;
    float* adst2 = ws + off; off += (size_t)NN * NH;
    int* ibase = (int*)(ws + off);
    int* deg   = ibase;                 // [NN]  \ adjacent so one zero_ints
    int* fill  = ibase + NN;            // [NN]  /
    int* offs  = ibase + 2 * NN;        // [NN]
    int* bsum  = ibase + 3 * NN;        // [256]
    int* esrc  = ibase + 3 * NN + 256;  // [NE]
    float* h2 = h1;                     // alias: h1 dead before gemm2 writes h2

    const int B = 256;
    constexpr int NB_SCAN = (NN + 255) / 256;   // 196

    // ---- CSR build (shared by both layers) ----
    zero_ints<<<128, B, 0, stream>>>(deg, 2 * NN);   // deg + fill
    hist_dst<<<(NE + B - 1) / B, B, 0, stream>>>(ei, deg);
    scan_blocks<<<NB_SCAN, 256, 0, stream>>>(deg, offs, bsum);
    scan_bsums<<<1, 256, 0, stream>>>(bsum, NB_SCAN);
    scan_add<<<NB_SCAN, 256, 0, stream>>>(offs, bsum);
    csr_scatter<<<(NE + B - 1) / B, B, 0, stream>>>(ei, offs, fill, esrc);

    // ---- layer 1 ----
    gemm_k128<128, false><<<(NN + 31) / 32, B, 0, stream>>>(
        x, W1, nullptr, as1, ad1, h1, asrc1, adst1, NN);
    gat_dst1<<<(NN * 64 + B - 1) / B, B, 0, stream>>>(esrc, offs, h1, asrc1, adst1, out1);

    // ---- layer 2 ----
    gemm_k128<64, true><<<(NN + 63) / 64, B, 0, stream>>>(
        out1, W2, b1, as2, ad2, h2, asrc2, adst2, NN);
    gat_dst2<<<(NN * 64 + B - 1) / B, B, 0, stream>>>(esrc, offs, h2, asrc2, adst2, b2, out);
}